// Round 1
// 279.775 us; speedup vs baseline: 1.4452x; 1.4452x over previous
//
#include <hip/hip_runtime.h>

typedef __attribute__((ext_vector_type(8))) short bf16x8;
typedef __attribute__((ext_vector_type(4))) short bf16x4;
typedef __attribute__((ext_vector_type(4))) float f32x4;

#define NPEDS 65536
#define SEQ 12
#define HD 128
#define ED 64
#define MBLK 64
#define P1 136  // h-row pitch in elems (272 B, 16B-aligned rows, bank-uniform b128 reads)
#define PD 72   // dec_in0 row pitch in elems (144 B)
#define NFRAG0 192
#define NFRAG1 132
#define WSB_BEFF_OFF ((NFRAG0 + NFRAG1) * 512)  // shorts; beff floats after frags

__device__ __forceinline__ short f2bf(float x) {
  unsigned u = __builtin_bit_cast(unsigned, x);
  u += 0x7FFFu + ((u >> 16) & 1u);  // round-to-nearest-even
  return (short)(u >> 16);
}
__device__ __forceinline__ float sigm(float x) {
  return __builtin_amdgcn_rcpf(1.0f + __expf(-x));
}
__device__ __forceinline__ float tanh_(float x) {
  return 1.0f - 2.0f * __builtin_amdgcn_rcpf(1.0f + __expf(2.0f * x));
}

// Physical elem position of logical k within a row (fragment-contiguous layout):
// lane (llo,lhi) fragment (kt) reads 8 contiguous elems at kt*32 + lhi*8.
__device__ __forceinline__ int pe_grp(int a) {
  // a = k>>2 (4-elem group); returns elem offset of that group
  return (a >> 3) * 32 + (a & 3) * 8 + ((a >> 2) & 1) * 4;
}

// wsB layout:
//  Part A (step 0), frags f0 = (cc*4+g)*6 + kt6, kt6<2 -> w_ih, else w_hh.
//  Part B (steps>=1) at +NFRAG0*512: gates f1 = (cc*4+g)*4 + kt (W_eff),
//    rel f1 = 128+kt (w_hp rows 0..1, rest zero).
//  b_eff[512] floats at +WSB_BEFF_OFF shorts.
__global__ void prep_kernel(const float* __restrict__ w_ih,
                            const float* __restrict__ w_hh,
                            const float* __restrict__ w_se,
                            const float* __restrict__ w_hp,
                            const float* __restrict__ b_ih,
                            const float* __restrict__ b_hh,
                            const float* __restrict__ b_se,
                            const float* __restrict__ b_hp,
                            short* __restrict__ wsB, float* __restrict__ beff) {
  int t = blockIdx.x * 256 + threadIdx.x;
  if (t < NFRAG0 * 64) {
    int frag = t >> 6, l = t & 63;
    int cc = frag / 24, g = (frag / 6) % 4, kt = frag % 6;
    int n = g * HD + cc * 16 + (l & 15);
    bf16x8 v;
#pragma unroll
    for (int e = 0; e < 8; ++e) {
      int k = kt * 32 + ((l >> 4) << 2) + (e & 3) + ((e >> 2) << 4);
      float x = (k < ED) ? w_ih[n * ED + k] : w_hh[n * HD + (k - ED)];
      v[e] = f2bf(x);
    }
    *(bf16x8*)(wsB + (size_t)frag * 512 + l * 8) = v;
  } else if (t < (NFRAG0 + NFRAG1) * 64) {
    int u = t - NFRAG0 * 64;
    int frag = u >> 6, l = u & 63;
    int llo = l & 15;
    int ks[8];
#pragma unroll
    for (int e = 0; e < 8; ++e)
      ks[e] = (frag & 3) * 32 + ((l >> 4) << 2) + (e & 3) + ((e >> 2) << 4);
    float acc[8];
    if (frag < 128) {
      int cc = frag >> 4, g = (frag >> 2) & 3;
      int n = g * HD + cc * 16 + llo;
#pragma unroll
      for (int e = 0; e < 8; ++e) acc[e] = w_hh[n * HD + ks[e]];
      for (int j = 0; j < ED; ++j) {
        float wij = w_ih[n * ED + j];
        float se0 = w_se[2 * j], se1 = w_se[2 * j + 1];
#pragma unroll
        for (int e = 0; e < 8; ++e)
          acc[e] += wij * (se0 * w_hp[ks[e]] + se1 * w_hp[HD + ks[e]]);
      }
    } else {
#pragma unroll
      for (int e = 0; e < 8; ++e)
        acc[e] = (llo < 2) ? w_hp[llo * HD + ks[e]] : 0.f;
    }
    bf16x8 v;
#pragma unroll
    for (int e = 0; e < 8; ++e) v[e] = f2bf(acc[e]);
    *(bf16x8*)(wsB + (size_t)(NFRAG0 + frag) * 512 + l * 8) = v;
  } else if (t < (NFRAG0 + NFRAG1) * 64 + 512) {
    int n = t - (NFRAG0 + NFRAG1) * 64;
    float s = b_ih[n] + b_hh[n];
    for (int j = 0; j < ED; ++j)
      s += w_ih[n * ED + j] *
           (b_se[j] + w_se[2 * j] * b_hp[0] + w_se[2 * j + 1] * b_hp[1]);
    beff[n] = s;
  }
}

__global__ __launch_bounds__(256, 2) void lstm_kernel(
    const float* __restrict__ lpr, const float* __restrict__ h0,
    const float* __restrict__ c0, const float* __restrict__ b_ih,
    const float* __restrict__ b_hh, const float* __restrict__ w_se,
    const float* __restrict__ b_se, const float* __restrict__ b_hp,
    const short* __restrict__ wsB, const float* __restrict__ beff,
    float* __restrict__ out) {
  __shared__ __align__(16) short hb[2][MBLK * P1];
  __shared__ __align__(16) short db[MBLK * PD];

  const int tid = threadIdx.x;
  const int w = tid >> 6;
  const int l = tid & 63;
  const int lhi = l >> 4;
  const int llo = l & 15;
  const int p0 = blockIdx.x * MBLK;

  // c0 -> registers (C-tile layout); biases (step-0 and folded)
  float creg[2][4][4], bias0[2][4], biasE[2][4];
#pragma unroll
  for (int cci = 0; cci < 2; ++cci) {
    const int cc = w * 2 + cci;
    const int col = cc * 16 + llo;
#pragma unroll
    for (int Mt = 0; Mt < 4; ++Mt)
#pragma unroll
      for (int r = 0; r < 4; ++r)
        creg[cci][Mt][r] = c0[(size_t)(p0 + Mt * 16 + lhi * 4 + r) * HD + col];
#pragma unroll
    for (int g = 0; g < 4; ++g) {
      int n = g * HD + col;
      bias0[cci][g] = b_ih[n] + b_hh[n];
      biasE[cci][g] = beff[n];
    }
  }
  const float bhp_l = (llo < 2) ? b_hp[llo] : 0.f;

  // stage h0 -> hb[0] (pe layout), vectorized: 2048 groups of 4 elems
#pragma unroll
  for (int i = 0; i < 8; ++i) {
    int grp = i * 256 + tid;
    int p = grp >> 5, a = grp & 31;
    f32x4 v = *(const f32x4*)(h0 + (size_t)(p0 + p) * HD + a * 4);
    bf16x4 s;
    s[0] = f2bf(v[0]); s[1] = f2bf(v[1]); s[2] = f2bf(v[2]); s[3] = f2bf(v[3]);
    *(bf16x4*)(&hb[0][p * P1 + pe_grp(a)]) = s;
  }
  // dec_in0 = lpr @ w_se.T + b_se -> db (pe layout): 1024 groups of 4
#pragma unroll
  for (int i = 0; i < 4; ++i) {
    int item = i * 256 + tid;
    int p = item >> 4, a = item & 15;
    float r0 = lpr[(size_t)(p0 + p) * 2 + 0];
    float r1 = lpr[(size_t)(p0 + p) * 2 + 1];
    bf16x4 s;
#pragma unroll
    for (int q = 0; q < 4; ++q) {
      int c = a * 4 + q;
      s[q] = f2bf(r0 * w_se[c * 2] + r1 * w_se[c * 2 + 1] + b_se[c]);
    }
    *(bf16x4*)(&db[p * PD + pe_grp(a)]) = s;
  }
  __syncthreads();

  auto lstm_update = [&](f32x4 (&acc)[4][4], int cci, short* An) {
    const int cc = w * 2 + cci;
    const int hoff = (cc >> 1) * 32 + (llo >> 2) * 8 + (cc & 1) * 4 + (llo & 3);
#pragma unroll
    for (int Mt = 0; Mt < 4; ++Mt)
#pragma unroll
      for (int r = 0; r < 4; ++r) {
        float gi = acc[0][Mt][r], gf = acc[1][Mt][r];
        float gg = acc[2][Mt][r], go = acc[3][Mt][r];
        float cn = sigm(gf) * creg[cci][Mt][r] + sigm(gi) * tanh_(gg);
        creg[cci][Mt][r] = cn;
        float hn = sigm(go) * tanh_(cn);
        An[(Mt * 16 + lhi * 4 + r) * P1 + hoff] = f2bf(hn);
      }
  };

  // ---- step 0: gates = dec_in0 @ w_ih.T + h0 @ w_hh.T + b (6 K-tiles) ----
  {
    short* An = hb[1];
#pragma unroll
    for (int cci = 0; cci < 2; ++cci) {
      const int cc = w * 2 + cci;
      f32x4 acc[4][4];
#pragma unroll
      for (int g = 0; g < 4; ++g) {
        float b = bias0[cci][g];
        f32x4 bv = {b, b, b, b};
#pragma unroll
        for (int Mt = 0; Mt < 4; ++Mt) acc[g][Mt] = bv;
      }
#pragma unroll
      for (int kt = 0; kt < 6; ++kt) {
        bf16x8 Af[4];
#pragma unroll
        for (int Mt = 0; Mt < 4; ++Mt) {
          const int row = Mt * 16 + llo;
          const short* ap = (kt < 2)
                                ? &db[row * PD + kt * 32 + lhi * 8]
                                : &hb[0][row * P1 + (kt - 2) * 32 + lhi * 8];
          Af[Mt] = *(const bf16x8*)ap;
        }
#pragma unroll
        for (int g = 0; g < 4; ++g) {
          bf16x8 Bf = *(const bf16x8*)(wsB +
                          (size_t)((cc * 4 + g) * 6 + kt) * 512 + l * 8);
#pragma unroll
          for (int Mt = 0; Mt < 4; ++Mt)
            acc[g][Mt] = __builtin_amdgcn_mfma_f32_16x16x32_bf16(
                Af[Mt], Bf, acc[g][Mt], 0, 0, 0);
        }
      }
      lstm_update(acc, cci, An);
    }
    __syncthreads();
  }

  // ---- steps 1..11: gates = h @ W_eff.T + b_eff (4 K-tiles) + rel chunk ----
  const short* wsB1 = wsB + (size_t)NFRAG0 * 512;
  for (int s = 1; s < SEQ; ++s) {
    const short* A = hb[s & 1];
    short* An = hb[(s + 1) & 1];
    bf16x8 Af[4][4];  // [kt][Mt], shared across both col-chunks and rel
#pragma unroll
    for (int kt = 0; kt < 4; ++kt)
#pragma unroll
      for (int Mt = 0; Mt < 4; ++Mt)
        Af[kt][Mt] =
            *(const bf16x8*)(&A[(Mt * 16 + llo) * P1 + kt * 32 + lhi * 8]);
#pragma unroll
    for (int cci = 0; cci < 2; ++cci) {
      const int cc = w * 2 + cci;
      f32x4 acc[4][4];
#pragma unroll
      for (int g = 0; g < 4; ++g) {
        float b = biasE[cci][g];
        f32x4 bv = {b, b, b, b};
#pragma unroll
        for (int Mt = 0; Mt < 4; ++Mt) acc[g][Mt] = bv;
      }
#pragma unroll
      for (int kt = 0; kt < 4; ++kt)
#pragma unroll
        for (int g = 0; g < 4; ++g) {
          bf16x8 Bf = *(const bf16x8*)(wsB1 +
                          (size_t)((cc * 4 + g) * 4 + kt) * 512 + l * 8);
#pragma unroll
          for (int Mt = 0; Mt < 4; ++Mt)
            acc[g][Mt] = __builtin_amdgcn_mfma_f32_16x16x32_bf16(
                Af[kt][Mt], Bf, acc[g][Mt], 0, 0, 0);
        }
      lstm_update(acc, cci, An);
    }
    // rel(s-1) = h(s) @ w_hp.T + b_hp  (extra 16-col chunk, wave 3)
    if (w == 3) {
      f32x4 ar[4];
#pragma unroll
      for (int Mt = 0; Mt < 4; ++Mt) ar[Mt] = {bhp_l, bhp_l, bhp_l, bhp_l};
#pragma unroll
      for (int kt = 0; kt < 4; ++kt) {
        bf16x8 Bf =
            *(const bf16x8*)(wsB1 + (size_t)(128 + kt) * 512 + l * 8);
#pragma unroll
        for (int Mt = 0; Mt < 4; ++Mt)
          ar[Mt] = __builtin_amdgcn_mfma_f32_16x16x32_bf16(Af[kt][Mt], Bf,
                                                           ar[Mt], 0, 0, 0);
      }
      if (llo < 2) {
#pragma unroll
        for (int Mt = 0; Mt < 4; ++Mt)
#pragma unroll
          for (int r = 0; r < 4; ++r)
            out[(size_t)(s - 1) * (NPEDS * 2) +
                (size_t)(p0 + Mt * 16 + lhi * 4 + r) * 2 + llo] = ar[Mt][r];
      }
    }
    __syncthreads();
  }

  // ---- epilogue: rel(11) from h(12) in hb[SEQ & 1] ----
  if (w == 3) {
    const short* A = hb[SEQ & 1];
    f32x4 ar[4];
#pragma unroll
    for (int Mt = 0; Mt < 4; ++Mt) ar[Mt] = {bhp_l, bhp_l, bhp_l, bhp_l};
#pragma unroll
    for (int kt = 0; kt < 4; ++kt) {
      bf16x8 Bf = *(const bf16x8*)(wsB1 + (size_t)(128 + kt) * 512 + l * 8);
#pragma unroll
      for (int Mt = 0; Mt < 4; ++Mt) {
        bf16x8 Afe =
            *(const bf16x8*)(&A[(Mt * 16 + llo) * P1 + kt * 32 + lhi * 8]);
        ar[Mt] = __builtin_amdgcn_mfma_f32_16x16x32_bf16(Afe, Bf, ar[Mt], 0,
                                                         0, 0);
      }
    }
    if (llo < 2) {
#pragma unroll
      for (int Mt = 0; Mt < 4; ++Mt)
#pragma unroll
        for (int r = 0; r < 4; ++r)
          out[(size_t)(SEQ - 1) * (NPEDS * 2) +
              (size_t)(p0 + Mt * 16 + lhi * 4 + r) * 2 + llo] = ar[Mt][r];
    }
  }
}

extern "C" void kernel_launch(void* const* d_in, const int* in_sizes, int n_in,
                              void* d_out, int out_size, void* d_ws,
                              size_t ws_size, hipStream_t stream) {
  // setup_inputs order:
  // 0 last_pos (unused), 1 last_pos_rel, 2 h0, 3 c0, 4 w_ih, 5 w_hh,
  // 6 b_ih, 7 b_hh, 8 w_se, 9 b_se, 10 w_hp, 11 b_hp
  const float* lpr = (const float*)d_in[1];
  const float* h0 = (const float*)d_in[2];
  const float* c0 = (const float*)d_in[3];
  const float* w_ih = (const float*)d_in[4];
  const float* w_hh = (const float*)d_in[5];
  const float* b_ih = (const float*)d_in[6];
  const float* b_hh = (const float*)d_in[7];
  const float* w_se = (const float*)d_in[8];
  const float* b_se = (const float*)d_in[9];
  const float* w_hp = (const float*)d_in[10];
  const float* b_hp = (const float*)d_in[11];
  short* wsB = (short*)d_ws;  // needs (192+132)*1024 + 2048 = 333824 bytes
  float* beff = (float*)((char*)d_ws + (size_t)WSB_BEFF_OFF * sizeof(short));
  float* out = (float*)d_out;

  prep_kernel<<<83, 256, 0, stream>>>(w_ih, w_hh, w_se, w_hp, b_ih, b_hh,
                                      b_se, b_hp, wsB, beff);
  lstm_kernel<<<NPEDS / MBLK, 256, 0, stream>>>(lpr, h0, c0, b_ih, b_hh, w_se,
                                                b_se, b_hp, wsB, beff, out);
}